// Round 15
// baseline (103.199 us; speedup 1.0000x reference)
//
#include <hip/hip_runtime.h>
#include <hip/hip_bf16.h>

typedef __bf16 bf16;
typedef bf16 bf16x4 __attribute__((ext_vector_type(4)));
typedef bf16 bf16x8 __attribute__((ext_vector_type(8)));
typedef float f32x4 __attribute__((ext_vector_type(4)));

#define GLOAD16(g, l) __builtin_amdgcn_global_load_lds( \
    (const __attribute__((address_space(1))) void*)(g),  \
    (__attribute__((address_space(3))) void*)(l), 16, 0, 0)

#define EXP2F(x) __builtin_amdgcn_exp2f(x)
#define MFMA16(a, b, c) __builtin_amdgcn_mfma_f32_16x16x32_bf16(a, b, c, 0, 0, 0)

// ---------------- prep: cast x + transpose-cast both weights ----------------
__global__ __launch_bounds__(256) void prep(const float* __restrict__ x,
                                            const float* __restrict__ Wqkv,
                                            const float* __restrict__ Wout,
                                            bf16* __restrict__ xb,
                                            bf16* __restrict__ wqkvT,
                                            bf16* __restrict__ woutT) {
  int id = blockIdx.x, tid = threadIdx.x;
  if (id < 2048) {
    int i = id * 256 + tid;
    const float4* p = (const float4*)x + (size_t)i * 2;
    float4 a = p[0], b = p[1];
    bf16x8 o;
    o[0] = (bf16)a.x; o[1] = (bf16)a.y; o[2] = (bf16)a.z; o[3] = (bf16)a.w;
    o[4] = (bf16)b.x; o[5] = (bf16)b.y; o[6] = (bf16)b.z; o[7] = (bf16)b.w;
    ((bf16x8*)xb)[i] = o;
  } else {
    __shared__ float tile[32][33];
    const float* src; bf16* dst; int N, j;
    if (id < 5120) { src = Wqkv; dst = wqkvT; N = 3072; j = id - 2048; }
    else           { src = Wout; dst = woutT; N = 1024; j = id - 5120; }
    int ntile = N / 32;
    int n0 = (j % ntile) * 32, k0 = (j / ntile) * 32;
    int tx = tid & 31, ty = tid >> 5;   // 32 x 8
#pragma unroll
    for (int i = 0; i < 4; i++)
      tile[ty + 8 * i][tx] = src[(size_t)(k0 + ty + 8 * i) * N + n0 + tx];
    __syncthreads();
#pragma unroll
    for (int i = 0; i < 4; i++)
      dst[(size_t)(n0 + ty + 8 * i) * 1024 + k0 + tx] = (bf16)tile[tx][ty + 8 * i];
  }
}

// ---- GEMM mainloop BK=64 (round-6 proven): C[128,128] += A * Bt^T ----
__device__ __forceinline__ void gemm_mainloop64(const bf16* __restrict__ A,
                                                const bf16* __restrict__ Bt,
                                                int K, int m0, int n0,
                                                f32x4 acc[4][4],
                                                bf16* As, bf16* Bs) {
  int tid = threadIdx.x;
  int lane = tid & 63;
  int wave = tid >> 6;
  int wr = wave >> 1, wc = wave & 1;
  int c16 = lane & 15, g = lane >> 4;
  f32x4 z = {0.f, 0.f, 0.f, 0.f};
#pragma unroll
  for (int m = 0; m < 4; m++)
#pragma unroll
    for (int n = 0; n < 4; n++) acc[m][n] = z;
  for (int k0 = 0; k0 < K; k0 += 64) {
#pragma unroll
    for (int i = 0; i < 4; i++) {
      int cc = tid + i * 256;          // 0..1023 chunks of 16B
      int r = cc >> 3, ch = cc & 7;
      int sc = ch ^ (r & 7);
      GLOAD16(A + (size_t)(m0 + r) * K + k0 + sc * 8, As + cc * 8);
    }
#pragma unroll
    for (int i = 0; i < 4; i++) {
      int cc = tid + i * 256;
      int r = cc >> 3, ch = cc & 7;
      int sc = ch ^ (r & 7);
      GLOAD16(Bt + (size_t)(n0 + r) * K + k0 + sc * 8, Bs + cc * 8);
    }
    __syncthreads();
#pragma unroll
    for (int h = 0; h < 2; h++) {
      bf16x8 af[4], bfr[4];
#pragma unroll
      for (int m = 0; m < 4; m++) {
        int ar = wr * 64 + m * 16 + c16;
        af[m] = *(const bf16x8*)((const char*)As + ar * 128 + (((h * 4 + g) ^ (ar & 7)) << 4));
      }
#pragma unroll
      for (int n = 0; n < 4; n++) {
        int br = wc * 64 + n * 16 + c16;
        bfr[n] = *(const bf16x8*)((const char*)Bs + br * 128 + (((h * 4 + g) ^ (br & 7)) << 4));
      }
      __builtin_amdgcn_s_setprio(1);
#pragma unroll
      for (int m = 0; m < 4; m++)
#pragma unroll
        for (int n = 0; n < 4; n++)
          acc[m][n] = MFMA16(af[m], bfr[n], acc[m][n]);
      __builtin_amdgcn_s_setprio(0);
    }
    __syncthreads();
  }
}

// ---- QKV GEMM: x[4096,1024] @ WqkvT[3072,1024]^T -> q,k scaled / vT ----
__global__ __launch_bounds__(256) void gemm_qkv(const bf16* __restrict__ A,
                                                const bf16* __restrict__ Bt,
                                                bf16* __restrict__ q,
                                                bf16* __restrict__ kk,
                                                bf16* __restrict__ vt) {
  __shared__ bf16 As[128 * 64];
  __shared__ bf16 Bs[128 * 64];
  int id = blockIdx.x;
  int xc = id & 7, k = id >> 3;            // k in [0,96)
  int bn = xc * 3 + (k % 3), bm = k / 3;   // bijective: bn [0,24), bm [0,32)
  int m0 = bm * 128, n0 = bn * 128;
  f32x4 acc[4][4];
  gemm_mainloop64(A, Bt, 1024, m0, n0, acc, As, Bs);
  int lane = threadIdx.x & 63;
  int wave = threadIdx.x >> 6;
  int wr = wave >> 1, wc = wave & 1;
  int c16 = lane & 15, g = lane >> 4;
  int which = n0 >> 10;
  const float QSCALE = 0.125f * 1.4426950408889634f;
  if (which == 2) {
#pragma unroll
    for (int m = 0; m < 4; m++)
#pragma unroll
      for (int n = 0; n < 4; n++) {
        int gm0 = m0 + wr * 64 + m * 16 + g * 4;
        int gn = n0 + wc * 64 + n * 16 + c16;
        int rem = gn & 1023, h = rem >> 6, d = rem & 63;
        int b = gm0 >> 11, t0 = gm0 & 2047;
        size_t bh = (size_t)(b * 16 + h);
        bf16x4 pv;
        pv[0] = (bf16)acc[m][n][0]; pv[1] = (bf16)acc[m][n][1];
        pv[2] = (bf16)acc[m][n][2]; pv[3] = (bf16)acc[m][n][3];
        *(bf16x4*)(vt + (bh * 64 + d) * 2048 + t0) = pv;
      }
  } else {
#pragma unroll
    for (int m = 0; m < 4; m++)
#pragma unroll
      for (int n = 0; n < 4; n++)
#pragma unroll
        for (int j = 0; j < 4; j++) {
          int gm = m0 + wr * 64 + m * 16 + g * 4 + j;
          int gn = n0 + wc * 64 + n * 16 + c16;
          int rem = gn & 1023, h = rem >> 6, d = rem & 63;
          int b = gm >> 11, t = gm & 2047;
          float v = acc[m][n][j];
          size_t bh = (size_t)(b * 16 + h);
          if (which == 0) q[(bh * 2048 + t) * 64 + d]  = (bf16)(v * QSCALE);
          else            kk[(bh * 2048 + t) * 64 + d] = (bf16)v;
        }
  }
}

// ---- final GEMM: attn[4096,1024] @ WoutT[1024,1024]^T -> out fp32 ----
// 64x128 tiles, grid 512 = 2 blocks/CU.
__global__ __launch_bounds__(256) void gemm_out(const bf16* __restrict__ A,
                                                const bf16* __restrict__ Bt,
                                                float* __restrict__ C) {
  __shared__ bf16 As[64 * 64];    // 8 KB
  __shared__ bf16 Bs[128 * 64];   // 16 KB
  int tid = threadIdx.x;
  int lane = tid & 63;
  int wave = tid >> 6;
  int wr = wave >> 1, wc = wave & 1;
  int c16 = lane & 15, g = lane >> 4;
  int id = blockIdx.x;
  int bn = id & 7, bm = id >> 3;      // bm 0..63
  int m0 = bm * 64, n0 = bn * 128;
  const int K = 1024;
  f32x4 acc[2][4];
  {
    f32x4 z = {0.f, 0.f, 0.f, 0.f};
#pragma unroll
    for (int m = 0; m < 2; m++)
#pragma unroll
      for (int n = 0; n < 4; n++) acc[m][n] = z;
  }
  for (int k0 = 0; k0 < K; k0 += 64) {
#pragma unroll
    for (int i = 0; i < 2; i++) {   // A tile 64x64 = 512 chunks
      int cc = tid + i * 256;
      int r = cc >> 3, ch = cc & 7;
      int sc = ch ^ (r & 7);
      GLOAD16(A + (size_t)(m0 + r) * K + k0 + sc * 8, As + cc * 8);
    }
#pragma unroll
    for (int i = 0; i < 4; i++) {   // B tile 128x64 = 1024 chunks
      int cc = tid + i * 256;
      int r = cc >> 3, ch = cc & 7;
      int sc = ch ^ (r & 7);
      GLOAD16(Bt + (size_t)(n0 + r) * K + k0 + sc * 8, Bs + cc * 8);
    }
    __syncthreads();
#pragma unroll
    for (int h = 0; h < 2; h++) {
      bf16x8 af[2], bfr[4];
#pragma unroll
      for (int m = 0; m < 2; m++) {
        int ar = wr * 32 + m * 16 + c16;
        af[m] = *(const bf16x8*)((const char*)As + ar * 128 + (((h * 4 + g) ^ (ar & 7)) << 4));
      }
#pragma unroll
      for (int n = 0; n < 4; n++) {
        int br = wc * 64 + n * 16 + c16;
        bfr[n] = *(const bf16x8*)((const char*)Bs + br * 128 + (((h * 4 + g) ^ (br & 7)) << 4));
      }
      __builtin_amdgcn_s_setprio(1);
#pragma unroll
      for (int m = 0; m < 2; m++)
#pragma unroll
        for (int n = 0; n < 4; n++)
          acc[m][n] = MFMA16(af[m], bfr[n], acc[m][n]);
      __builtin_amdgcn_s_setprio(0);
    }
    __syncthreads();
  }
#pragma unroll
  for (int m = 0; m < 2; m++)
#pragma unroll
    for (int n = 0; n < 4; n++)
#pragma unroll
      for (int j = 0; j < 4; j++) {
        int gm = m0 + wr * 32 + m * 16 + g * 4 + j;
        int gn = n0 + wc * 64 + n * 16 + c16;
        C[(size_t)gm * 1024 + gn] = acc[m][n][j];
      }
}

// ---------------- flash attention v12 (32 q-rows per wave: LDS-BW fix) ----------------
// attn is LDS-BW bound: every wave re-reads the full K/V tile. v12 uses
// 4 waves x 32 q-rows (m in {0,1}) so each K/V fragment read feeds 2x the
// MFMAs: per-block LDS traffic 160KB -> 96KB per tile. 256 thr, grid 512
// (same XCD decode), LDS 80KB = 2 blocks/CU. Fixed-max softmax (no running
// max), per-lane l partials, 2 tiles per barrier interval, 4 K/V buffers.
__global__ __launch_bounds__(256) void attn(const bf16* __restrict__ q,
                                            const bf16* __restrict__ kk,
                                            const bf16* __restrict__ vt,
                                            bf16* __restrict__ out) {
  __shared__ bf16 Ks[4][64 * 64];   // 32 KB (chunk-XOR swizzled)
  __shared__ bf16 Vs[4][64 * 64];   // 32 KB (chunk-XOR swizzled)
  __shared__ bf16 Ps[4 * 32 * 64];  // 16 KB: per-wave 32x64 P tiles
  int tid = threadIdx.x, lane = tid & 63, w = tid >> 6;
  int c16 = lane & 15, g = (lane >> 4) & 3, g4 = g * 4;

  // ---- XCD-aware decode (bijection on 512 blocks) ----
  int id = blockIdx.x;
  int c = id & 7;
  int k = id >> 3;
  int s = k >> 5;
  int j5 = k & 31;
  int bxi = j5 & 15, b2 = j5 >> 4;
  int bx = s ? (15 - bxi) : bxi;       // pairs sum to 15 (load balance)
  int bh = 4 * c + 2 * b2 + s;         // 4 bh per XCD (K/V L2-resident)
  int q0 = bx * 128;

  const bf16* qb = q  + (size_t)bh * 2048 * 64;
  const bf16* kb = kk + (size_t)bh * 2048 * 64;
  const bf16* vb = vt + (size_t)bh * 64 * 2048;
  int nt = 2 * bx + 2;              // even
  int ns = nt >> 1;

  // ---- prologue: Q frags (2 m-chunks) to registers; stage K/V tiles 0,1 ----
  int qlo = q0 + w * 32;            // wave owns rows [qlo, qlo+32)
  bf16x8 qf[2][2];
#pragma unroll
  for (int m = 0; m < 2; m++)
#pragma unroll
    for (int ks = 0; ks < 2; ks++)
      qf[m][ks] = *(const bf16x8*)(qb + (size_t)(qlo + m * 16 + c16) * 64 + ks * 32 + g * 8);
#pragma unroll
  for (int i = 0; i < 2; i++) {
    int cc = tid + i * 256;          // 512 chunks per 64x64 tile
    int r = cc >> 3;
    int sw = ((cc & 7) ^ (r & 7)) * 8;
    GLOAD16(kb + (size_t)r * 64 + sw, Ks[0] + cc * 8);
    GLOAD16(vb + (size_t)r * 2048 + sw, Vs[0] + cc * 8);
    GLOAD16(kb + (size_t)(64 + r) * 64 + sw, Ks[1] + cc * 8);
    GLOAD16(vb + (size_t)r * 2048 + 64 + sw, Vs[1] + cc * 8);
  }
  __syncthreads();

  f32x4 o[2][4];
  float lrun[2] = {0.f, 0.f};       // per-lane partial row-sums
  {
    f32x4 z = {0.f, 0.f, 0.f, 0.f};
#pragma unroll
    for (int m = 0; m < 2; m++)
#pragma unroll
      for (int n = 0; n < 4; n++) o[m][n] = z;
  }
  bf16* Pw = Ps + w * 2048;         // 32x64 per-wave P tile

  for (int st = 0; st < ns; ++st) {
    if (st + 1 < ns) {              // prefetch next pair of tiles
      int sn = st * 128 + 128;
      int nb = (2 * st + 2) & 3;    // and nb+1
#pragma unroll
      for (int i = 0; i < 2; i++) {
        int cc = tid + i * 256;
        int r = cc >> 3;
        int sw = ((cc & 7) ^ (r & 7)) * 8;
        GLOAD16(kb + (size_t)(sn + r) * 64 + sw, Ks[nb] + cc * 8);
        GLOAD16(vb + (size_t)r * 2048 + sn + sw, Vs[nb] + cc * 8);
        GLOAD16(kb + (size_t)(sn + 64 + r) * 64 + sw, Ks[nb + 1] + cc * 8);
        GLOAD16(vb + (size_t)r * 2048 + sn + 64 + sw, Vs[nb + 1] + cc * 8);
      }
    }
#pragma unroll
    for (int half = 0; half < 2; ++half) {
      int t = 2 * st + half;
      int s0 = t * 64;
      if (s0 > qlo + 31) continue;   // wave-uniform causal skip
      const char* Kb = (const char*)Ks[t & 3];
      const char* Vb = (const char*)Vs[t & 3];
      // ---- QK^T: S[m][n]: row s = s0+n*16+g4+j, col q = qlo+m*16+c16 ----
      f32x4 S[2][4];
      {
        f32x4 z = {0.f, 0.f, 0.f, 0.f};
#pragma unroll
        for (int m = 0; m < 2; m++)
#pragma unroll
          for (int n = 0; n < 4; n++) S[m][n] = z;
      }
      __builtin_amdgcn_s_setprio(1);
#pragma unroll
      for (int ks = 0; ks < 2; ks++) {
        bf16x8 kf[4];
#pragma unroll
        for (int n = 0; n < 4; n++) {
          int srow = n * 16 + c16;
          kf[n] = *(const bf16x8*)(Kb + srow * 128 + (((ks * 4 + g) ^ (srow & 7)) << 4));
        }
#pragma unroll
        for (int m = 0; m < 2; m++)
#pragma unroll
          for (int n = 0; n < 4; n++)
            S[m][n] = MFMA16(kf[n], qf[m][ks], S[m][n]);
      }
      __builtin_amdgcn_s_setprio(0);
      // ---- mask + fixed-max softmax + P write ----
      bool diag = (s0 + 63 > qlo);   // wave-uniform
#pragma unroll
      for (int m = 0; m < 2; m++) {
        int qr = qlo + m * 16 + c16;
        if (diag) {
#pragma unroll
          for (int n = 0; n < 4; n++)
#pragma unroll
            for (int rr = 0; rr < 4; rr++)
              if (s0 + n * 16 + g4 + rr > qr) S[m][n][rr] = -__builtin_inff();
        }
        float p[4][4];
        float rs = 0.f;
#pragma unroll
        for (int n = 0; n < 4; n++)
#pragma unroll
          for (int rr = 0; rr < 4; rr++) {
            p[n][rr] = EXP2F(S[m][n][rr]);
            rs += p[n][rr];
          }
        lrun[m] += rs;
        int rp = m * 16 + c16;
#pragma unroll
        for (int n = 0; n < 4; n++) {
          bf16x4 pw;
          pw[0] = (bf16)p[n][0]; pw[1] = (bf16)p[n][1];
          pw[2] = (bf16)p[n][2]; pw[3] = (bf16)p[n][3];
          *(bf16x4*)(Pw + rp * 64 + (((2 * n + (g >> 1)) ^ (c16 & 7)) * 8) + (g & 1) * 4) = pw;
        }
      }
      // ---- PV: o[m][n]: row q-offset = g4+j, col d = n*16+c16 ----
      __builtin_amdgcn_s_setprio(1);
#pragma unroll
      for (int ks = 0; ks < 2; ks++) {
        bf16x8 vf[4];
#pragma unroll
        for (int n = 0; n < 4; n++) {
          int drow = n * 16 + c16;
          vf[n] = *(const bf16x8*)(Vb + drow * 128 + (((ks * 4 + g) ^ (drow & 7)) << 4));
        }
#pragma unroll
        for (int m = 0; m < 2; m++) {
          bf16x8 pf = *(const bf16x8*)(Pw + (m * 16 + c16) * 64 + (((ks * 4 + g) ^ (c16 & 7)) * 8));
#pragma unroll
          for (int n = 0; n < 4; n++)
            o[m][n] = MFMA16(pf, vf[n], o[m][n]);
        }
      }
      __builtin_amdgcn_s_setprio(0);
    }
    if (st + 1 < ns) {
      asm volatile("s_waitcnt vmcnt(0)" ::: "memory");  // next pair staged
      __builtin_amdgcn_s_barrier();
      __builtin_amdgcn_sched_barrier(0);
    }
  }
  // ---- epilogue: reduce l once, then store ----
  int b = bh >> 4, h = bh & 15;
#pragma unroll
  for (int m = 0; m < 2; m++) {
    float lm = lrun[m];
    lm += __shfl_xor(lm, 16);
    lm += __shfl_xor(lm, 32);    // lanes with same c16 hold row (qlo+m*16+c16)'s l
#pragma unroll
    for (int j = 0; j < 4; j++) {
      float lv = __shfl(lm, (lane & 48) | (g4 + j));
      float inv = 1.f / lv;
      int t = qlo + m * 16 + g4 + j;
#pragma unroll
      for (int n = 0; n < 4; n++) {
        int col = h * 64 + n * 16 + c16;
        out[((size_t)(b * 2048 + t)) * 1024 + col] = (bf16)(o[m][n][j] * inv);
      }
    }
  }
}

extern "C" void kernel_launch(void* const* d_in, const int* in_sizes, int n_in,
                              void* d_out, int out_size, void* d_ws, size_t ws_size,
                              hipStream_t stream) {
  const float* x    = (const float*)d_in[0];
  const float* Wqkv = (const float*)d_in[1];
  const float* Wout = (const float*)d_in[2];
  float* outp = (float*)d_out;
  char* ws = (char*)d_ws;
  const size_t MB = 1024 * 1024;
  bf16* xb    = (bf16*)(ws);             // 8 MB [4096][1024]; later reused as attn out
  bf16* wqkvT = (bf16*)(ws + 8 * MB);    // 6 MB [3072][1024]
  bf16* woutT = (bf16*)(ws + 14 * MB);   // 2 MB [1024][1024]
  bf16* qb    = (bf16*)(ws + 16 * MB);   // 8 MB [32][2048][64] (scaled 0.125*log2e)
  bf16* kb    = (bf16*)(ws + 24 * MB);   // 8 MB [32][2048][64]
  bf16* vtb   = (bf16*)(ws + 32 * MB);   // 8 MB [32][64][2048]

  hipLaunchKernelGGL(prep, dim3(6144), dim3(256), 0, stream,
                     x, Wqkv, Wout, xb, wqkvT, woutT);
  hipLaunchKernelGGL(gemm_qkv, dim3(768), dim3(256), 0, stream,
                     xb, wqkvT, qb, kb, vtb);
  hipLaunchKernelGGL(attn, dim3(512), dim3(256), 0, stream,
                     qb, kb, vtb, xb);
  hipLaunchKernelGGL(gemm_out, dim3(512), dim3(256), 0, stream,
                     xb, woutT, outp);
}

// Round 16
// 101.420 us; speedup vs baseline: 1.0175x; 1.0175x over previous
//
#include <hip/hip_runtime.h>
#include <hip/hip_bf16.h>

typedef __bf16 bf16;
typedef bf16 bf16x4 __attribute__((ext_vector_type(4)));
typedef bf16 bf16x8 __attribute__((ext_vector_type(8)));
typedef float f32x4 __attribute__((ext_vector_type(4)));
typedef float f32x16 __attribute__((ext_vector_type(16)));
typedef unsigned int u32x4 __attribute__((ext_vector_type(4)));

#define GLOAD16(g, l) __builtin_amdgcn_global_load_lds( \
    (const __attribute__((address_space(1))) void*)(g),  \
    (__attribute__((address_space(3))) void*)(l), 16, 0, 0)

#define EXP2F(x) __builtin_amdgcn_exp2f(x)
#define MFMA16(a, b, c) __builtin_amdgcn_mfma_f32_16x16x32_bf16(a, b, c, 0, 0, 0)
#define MFMA32(a, b, c) __builtin_amdgcn_mfma_f32_32x32x16_bf16(a, b, c, 0, 0, 0)

// ---------------- prep: cast x + transpose-cast both weights ----------------
__global__ __launch_bounds__(256) void prep(const float* __restrict__ x,
                                            const float* __restrict__ Wqkv,
                                            const float* __restrict__ Wout,
                                            bf16* __restrict__ xb,
                                            bf16* __restrict__ wqkvT,
                                            bf16* __restrict__ woutT) {
  int id = blockIdx.x, tid = threadIdx.x;
  if (id < 2048) {
    int i = id * 256 + tid;
    const float4* p = (const float4*)x + (size_t)i * 2;
    float4 a = p[0], b = p[1];
    bf16x8 o;
    o[0] = (bf16)a.x; o[1] = (bf16)a.y; o[2] = (bf16)a.z; o[3] = (bf16)a.w;
    o[4] = (bf16)b.x; o[5] = (bf16)b.y; o[6] = (bf16)b.z; o[7] = (bf16)b.w;
    ((bf16x8*)xb)[i] = o;
  } else {
    __shared__ float tile[32][33];
    const float* src; bf16* dst; int N, j;
    if (id < 5120) { src = Wqkv; dst = wqkvT; N = 3072; j = id - 2048; }
    else           { src = Wout; dst = woutT; N = 1024; j = id - 5120; }
    int ntile = N / 32;
    int n0 = (j % ntile) * 32, k0 = (j / ntile) * 32;
    int tx = tid & 31, ty = tid >> 5;   // 32 x 8
#pragma unroll
    for (int i = 0; i < 4; i++)
      tile[ty + 8 * i][tx] = src[(size_t)(k0 + ty + 8 * i) * N + n0 + tx];
    __syncthreads();
#pragma unroll
    for (int i = 0; i < 4; i++)
      dst[(size_t)(n0 + ty + 8 * i) * 1024 + k0 + tx] = (bf16)tile[tx][ty + 8 * i];
  }
}

// ---- GEMM mainloop BK=64 (round-6 proven): C[128,128] += A * Bt^T ----
__device__ __forceinline__ void gemm_mainloop64(const bf16* __restrict__ A,
                                                const bf16* __restrict__ Bt,
                                                int K, int m0, int n0,
                                                f32x4 acc[4][4],
                                                bf16* As, bf16* Bs) {
  int tid = threadIdx.x;
  int lane = tid & 63;
  int wave = tid >> 6;
  int wr = wave >> 1, wc = wave & 1;
  int c16 = lane & 15, g = lane >> 4;
  f32x4 z = {0.f, 0.f, 0.f, 0.f};
#pragma unroll
  for (int m = 0; m < 4; m++)
#pragma unroll
    for (int n = 0; n < 4; n++) acc[m][n] = z;
  for (int k0 = 0; k0 < K; k0 += 64) {
#pragma unroll
    for (int i = 0; i < 4; i++) {
      int cc = tid + i * 256;          // 0..1023 chunks of 16B
      int r = cc >> 3, ch = cc & 7;
      int sc = ch ^ (r & 7);
      GLOAD16(A + (size_t)(m0 + r) * K + k0 + sc * 8, As + cc * 8);
    }
#pragma unroll
    for (int i = 0; i < 4; i++) {
      int cc = tid + i * 256;
      int r = cc >> 3, ch = cc & 7;
      int sc = ch ^ (r & 7);
      GLOAD16(Bt + (size_t)(n0 + r) * K + k0 + sc * 8, Bs + cc * 8);
    }
    __syncthreads();
#pragma unroll
    for (int h = 0; h < 2; h++) {
      bf16x8 af[4], bfr[4];
#pragma unroll
      for (int m = 0; m < 4; m++) {
        int ar = wr * 64 + m * 16 + c16;
        af[m] = *(const bf16x8*)((const char*)As + ar * 128 + (((h * 4 + g) ^ (ar & 7)) << 4));
      }
#pragma unroll
      for (int n = 0; n < 4; n++) {
        int br = wc * 64 + n * 16 + c16;
        bfr[n] = *(const bf16x8*)((const char*)Bs + br * 128 + (((h * 4 + g) ^ (br & 7)) << 4));
      }
      __builtin_amdgcn_s_setprio(1);
#pragma unroll
      for (int m = 0; m < 4; m++)
#pragma unroll
        for (int n = 0; n < 4; n++)
          acc[m][n] = MFMA16(af[m], bfr[n], acc[m][n]);
      __builtin_amdgcn_s_setprio(0);
    }
    __syncthreads();
  }
}

// ---- QKV GEMM: x[4096,1024] @ WqkvT[3072,1024]^T -> q,k scaled / vT ----
__global__ __launch_bounds__(256) void gemm_qkv(const bf16* __restrict__ A,
                                                const bf16* __restrict__ Bt,
                                                bf16* __restrict__ q,
                                                bf16* __restrict__ kk,
                                                bf16* __restrict__ vt) {
  __shared__ bf16 As[128 * 64];
  __shared__ bf16 Bs[128 * 64];
  int id = blockIdx.x;
  int xc = id & 7, k = id >> 3;            // k in [0,96)
  int bn = xc * 3 + (k % 3), bm = k / 3;   // bijective: bn [0,24), bm [0,32)
  int m0 = bm * 128, n0 = bn * 128;
  f32x4 acc[4][4];
  gemm_mainloop64(A, Bt, 1024, m0, n0, acc, As, Bs);
  int lane = threadIdx.x & 63;
  int wave = threadIdx.x >> 6;
  int wr = wave >> 1, wc = wave & 1;
  int c16 = lane & 15, g = lane >> 4;
  int which = n0 >> 10;
  const float QSCALE = 0.125f * 1.4426950408889634f;
  if (which == 2) {
#pragma unroll
    for (int m = 0; m < 4; m++)
#pragma unroll
      for (int n = 0; n < 4; n++) {
        int gm0 = m0 + wr * 64 + m * 16 + g * 4;
        int gn = n0 + wc * 64 + n * 16 + c16;
        int rem = gn & 1023, h = rem >> 6, d = rem & 63;
        int b = gm0 >> 11, t0 = gm0 & 2047;
        size_t bh = (size_t)(b * 16 + h);
        bf16x4 pv;
        pv[0] = (bf16)acc[m][n][0]; pv[1] = (bf16)acc[m][n][1];
        pv[2] = (bf16)acc[m][n][2]; pv[3] = (bf16)acc[m][n][3];
        *(bf16x4*)(vt + (bh * 64 + d) * 2048 + t0) = pv;
      }
  } else {
#pragma unroll
    for (int m = 0; m < 4; m++)
#pragma unroll
      for (int n = 0; n < 4; n++)
#pragma unroll
        for (int j = 0; j < 4; j++) {
          int gm = m0 + wr * 64 + m * 16 + g * 4 + j;
          int gn = n0 + wc * 64 + n * 16 + c16;
          int rem = gn & 1023, h = rem >> 6, d = rem & 63;
          int b = gm >> 11, t = gm & 2047;
          float v = acc[m][n][j];
          size_t bh = (size_t)(b * 16 + h);
          if (which == 0) q[(bh * 2048 + t) * 64 + d]  = (bf16)(v * QSCALE);
          else            kk[(bh * 2048 + t) * 64 + d] = (bf16)v;
        }
  }
}

// ---- final GEMM: attn[4096,1024] @ WoutT[1024,1024]^T -> out fp32 ----
// 64x128 tiles, grid 512 = 2 blocks/CU.
__global__ __launch_bounds__(256) void gemm_out(const bf16* __restrict__ A,
                                                const bf16* __restrict__ Bt,
                                                float* __restrict__ C) {
  __shared__ bf16 As[64 * 64];    // 8 KB
  __shared__ bf16 Bs[128 * 64];   // 16 KB
  int tid = threadIdx.x;
  int lane = tid & 63;
  int wave = tid >> 6;
  int wr = wave >> 1, wc = wave & 1;
  int c16 = lane & 15, g = lane >> 4;
  int id = blockIdx.x;
  int bn = id & 7, bm = id >> 3;      // bm 0..63
  int m0 = bm * 64, n0 = bn * 128;
  const int K = 1024;
  f32x4 acc[2][4];
  {
    f32x4 z = {0.f, 0.f, 0.f, 0.f};
#pragma unroll
    for (int m = 0; m < 2; m++)
#pragma unroll
      for (int n = 0; n < 4; n++) acc[m][n] = z;
  }
  for (int k0 = 0; k0 < K; k0 += 64) {
#pragma unroll
    for (int i = 0; i < 2; i++) {   // A tile 64x64 = 512 chunks
      int cc = tid + i * 256;
      int r = cc >> 3, ch = cc & 7;
      int sc = ch ^ (r & 7);
      GLOAD16(A + (size_t)(m0 + r) * K + k0 + sc * 8, As + cc * 8);
    }
#pragma unroll
    for (int i = 0; i < 4; i++) {   // B tile 128x64 = 1024 chunks
      int cc = tid + i * 256;
      int r = cc >> 3, ch = cc & 7;
      int sc = ch ^ (r & 7);
      GLOAD16(Bt + (size_t)(n0 + r) * K + k0 + sc * 8, Bs + cc * 8);
    }
    __syncthreads();
#pragma unroll
    for (int h = 0; h < 2; h++) {
      bf16x8 af[2], bfr[4];
#pragma unroll
      for (int m = 0; m < 2; m++) {
        int ar = wr * 32 + m * 16 + c16;
        af[m] = *(const bf16x8*)((const char*)As + ar * 128 + (((h * 4 + g) ^ (ar & 7)) << 4));
      }
#pragma unroll
      for (int n = 0; n < 4; n++) {
        int br = wc * 64 + n * 16 + c16;
        bfr[n] = *(const bf16x8*)((const char*)Bs + br * 128 + (((h * 4 + g) ^ (br & 7)) << 4));
      }
      __builtin_amdgcn_s_setprio(1);
#pragma unroll
      for (int m = 0; m < 2; m++)
#pragma unroll
        for (int n = 0; n < 4; n++)
          acc[m][n] = MFMA16(af[m], bfr[n], acc[m][n]);
      __builtin_amdgcn_s_setprio(0);
    }
    __syncthreads();
  }
#pragma unroll
  for (int m = 0; m < 2; m++)
#pragma unroll
    for (int n = 0; n < 4; n++)
#pragma unroll
      for (int j = 0; j < 4; j++) {
        int gm = m0 + wr * 32 + m * 16 + g * 4 + j;
        int gn = n0 + wc * 64 + n * 16 + c16;
        C[(size_t)gm * 1024 + gn] = acc[m][n][j];
      }
}

// ---------------- flash attention v13 (32x32 MFMA, in-register P) ----------------
// 512 blocks x 256 thr (4 waves x 32 q-rows). Swapped QK^T with 32x32x16:
// A = K (rows s), B = Q (cols q=lane&31) -> lane's S column is its own q row.
// Fixed-max softmax: exp2 + per-lane partial l (reduced once, shfl_xor 32).
// PV: A = V^T (rows d), B = P^T built IN REGISTERS per k-step via
// 4x v_cvt_pk_bf16_f32 + 2x v_permlane32_swap_b32 (no P LDS traffic).
// K/V LDS traffic per unit work is HALF of the 16x16 version. 64 KB LDS,
// 2 blocks/CU; 2 tiles per barrier interval, 4 K/V buffers (v12 staging).
__global__ __launch_bounds__(256) void attn(const bf16* __restrict__ q,
                                            const bf16* __restrict__ kk,
                                            const bf16* __restrict__ vt,
                                            bf16* __restrict__ out) {
  __shared__ bf16 Ks[4][64 * 64];   // 32 KB (chunk-XOR swizzled)
  __shared__ bf16 Vs[4][64 * 64];   // 32 KB (chunk-XOR swizzled)
  int tid = threadIdx.x, lane = tid & 63, w = tid >> 6;
  int ql = lane & 31, hi = lane >> 5;

  // ---- XCD-aware decode (bijection on 512 blocks) ----
  int id = blockIdx.x;
  int c = id & 7;
  int k = id >> 3;
  int s = k >> 5;
  int j5 = k & 31;
  int bxi = j5 & 15, b2 = j5 >> 4;
  int bx = s ? (15 - bxi) : bxi;       // pairs sum to 15 (load balance)
  int bh = 4 * c + 2 * b2 + s;         // 4 bh per XCD (K/V L2-resident)
  int q0 = bx * 128;

  const bf16* qb = q  + (size_t)bh * 2048 * 64;
  const bf16* kb = kk + (size_t)bh * 2048 * 64;
  const bf16* vb = vt + (size_t)bh * 64 * 2048;
  int nt = 2 * bx + 2;              // even
  int ns = nt >> 1;

  int qlo = q0 + w * 32;            // wave owns q rows [qlo, qlo+32)
  int qg = qlo + ql;                // this lane's q row

  // ---- Q frags to registers: B-operand, col q=ql, k d = j*16 + hi*8 + e ----
  bf16x8 qf[4];
#pragma unroll
  for (int j = 0; j < 4; j++)
    qf[j] = *(const bf16x8*)(qb + (size_t)qg * 64 + j * 16 + hi * 8);

  // ---- stage K/V tiles 0,1 ----
#pragma unroll
  for (int i = 0; i < 2; i++) {
    int cc = tid + i * 256;          // 512 chunks per 64x64 tile
    int r = cc >> 3;
    int sw = ((cc & 7) ^ (r & 7)) * 8;
    GLOAD16(kb + (size_t)r * 64 + sw, Ks[0] + cc * 8);
    GLOAD16(vb + (size_t)r * 2048 + sw, Vs[0] + cc * 8);
    GLOAD16(kb + (size_t)(64 + r) * 64 + sw, Ks[1] + cc * 8);
    GLOAD16(vb + (size_t)r * 2048 + 64 + sw, Vs[1] + cc * 8);
  }
  __syncthreads();

  f32x16 o[2];
#pragma unroll
  for (int i = 0; i < 16; i++) { o[0][i] = 0.f; o[1][i] = 0.f; }
  float lsum = 0.f;

  for (int st = 0; st < ns; ++st) {
    if (st + 1 < ns) {              // prefetch next pair of tiles
      int sn = st * 128 + 128;
      int nb = (2 * st + 2) & 3;    // and nb+1
#pragma unroll
      for (int i = 0; i < 2; i++) {
        int cc = tid + i * 256;
        int r = cc >> 3;
        int sw = ((cc & 7) ^ (r & 7)) * 8;
        GLOAD16(kb + (size_t)(sn + r) * 64 + sw, Ks[nb] + cc * 8);
        GLOAD16(vb + (size_t)r * 2048 + sn + sw, Vs[nb] + cc * 8);
        GLOAD16(kb + (size_t)(sn + 64 + r) * 64 + sw, Ks[nb + 1] + cc * 8);
        GLOAD16(vb + (size_t)r * 2048 + sn + 64 + sw, Vs[nb + 1] + cc * 8);
      }
    }
#pragma unroll
    for (int half = 0; half < 2; ++half) {
      int t = 2 * st + half;
      int s0 = t * 64;
      if (s0 > qlo + 31) continue;   // wave-uniform causal skip
      const char* Kb = (const char*)Ks[t & 3];
      const char* Vb = (const char*)Vs[t & 3];
      // ---- QK^T: S[sb] col q=ql, row s = sb*32 + (r&3)+8*(r>>2)+4*hi ----
      f32x16 S[2];
#pragma unroll
      for (int i = 0; i < 16; i++) { S[0][i] = 0.f; S[1][i] = 0.f; }
      __builtin_amdgcn_s_setprio(1);
#pragma unroll
      for (int j = 0; j < 4; j++) {    // k-step over d
        int row0 = ql, row1 = 32 + ql;
        bf16x8 kf0 = *(const bf16x8*)(Kb + row0 * 128 + (((2 * j + hi) ^ (row0 & 7)) << 4));
        bf16x8 kf1 = *(const bf16x8*)(Kb + row1 * 128 + (((2 * j + hi) ^ (row1 & 7)) << 4));
        S[0] = MFMA32(kf0, qf[j], S[0]);
        S[1] = MFMA32(kf1, qf[j], S[1]);
      }
      __builtin_amdgcn_s_setprio(0);
      // ---- causal mask (diag tiles only, wave-uniform test) ----
      if (s0 + 63 > qlo) {
#pragma unroll
        for (int sb = 0; sb < 2; sb++)
#pragma unroll
          for (int r = 0; r < 16; r++) {
            int sg = s0 + sb * 32 + (r & 3) + 8 * (r >> 2) + 4 * hi;
            if (sg > qg) S[sb][r] = -__builtin_inff();
          }
      }
      // ---- fixed-max softmax: P = exp2(S) in place; per-lane l partial ----
#pragma unroll
      for (int sb = 0; sb < 2; sb++)
#pragma unroll
        for (int r = 0; r < 16; r++) {
          float pv2 = EXP2F(S[sb][r]);
          S[sb][r] = pv2;
          lsum += pv2;
        }
      // ---- PV: per k-step j (s 16j..16j+15): build P^T B-frag in regs ----
      __builtin_amdgcn_s_setprio(1);
#pragma unroll
      for (int j = 0; j < 4; j++) {
        int sb = j >> 1, rb = (j & 1) * 8;
        unsigned pa, pb, pc, pd;
        asm("v_cvt_pk_bf16_f32 %0, %1, %2" : "=v"(pa) : "v"(S[sb][rb + 0]), "v"(S[sb][rb + 1]));
        asm("v_cvt_pk_bf16_f32 %0, %1, %2" : "=v"(pb) : "v"(S[sb][rb + 2]), "v"(S[sb][rb + 3]));
        asm("v_cvt_pk_bf16_f32 %0, %1, %2" : "=v"(pc) : "v"(S[sb][rb + 4]), "v"(S[sb][rb + 5]));
        asm("v_cvt_pk_bf16_f32 %0, %1, %2" : "=v"(pd) : "v"(S[sb][rb + 6]), "v"(S[sb][rb + 7]));
        asm("v_permlane32_swap_b32 %0, %1" : "+v"(pa), "+v"(pc));
        asm("v_permlane32_swap_b32 %0, %1" : "+v"(pb), "+v"(pd));
        union { u32x4 u; bf16x8 h; } pu;
        pu.u[0] = pa; pu.u[1] = pb; pu.u[2] = pc; pu.u[3] = pd;
        int row0 = ql, row1 = 32 + ql;
        bf16x8 vf0 = *(const bf16x8*)(Vb + row0 * 128 + (((2 * j + hi) ^ (row0 & 7)) << 4));
        bf16x8 vf1 = *(const bf16x8*)(Vb + row1 * 128 + (((2 * j + hi) ^ (row1 & 7)) << 4));
        o[0] = MFMA32(vf0, pu.h, o[0]);
        o[1] = MFMA32(vf1, pu.h, o[1]);
      }
      __builtin_amdgcn_s_setprio(0);
    }
    if (st + 1 < ns) {
      asm volatile("s_waitcnt vmcnt(0)" ::: "memory");  // next pair staged
      __builtin_amdgcn_s_barrier();
      __builtin_amdgcn_sched_barrier(0);
    }
  }
  // ---- epilogue: l reduce (one swap), store O^T: row d, col q=ql ----
  lsum += __shfl_xor(lsum, 32);      // halves split s -> combine
  float inv = 1.f / lsum;
  int b = bh >> 4, h = bh & 15;
  size_t rowbase = ((size_t)(b * 2048 + qg)) * 1024 + h * 64;
#pragma unroll
  for (int db = 0; db < 2; db++)
#pragma unroll
    for (int qd = 0; qd < 4; qd++) {
      bf16x4 pv;
#pragma unroll
      for (int i = 0; i < 4; i++) pv[i] = (bf16)(o[db][4 * qd + i] * inv);
      *(bf16x4*)(out + rowbase + db * 32 + 8 * qd + 4 * hi) = pv;
    }
}

extern "C" void kernel_launch(void* const* d_in, const int* in_sizes, int n_in,
                              void* d_out, int out_size, void* d_ws, size_t ws_size,
                              hipStream_t stream) {
  const float* x    = (const float*)d_in[0];
  const float* Wqkv = (const float*)d_in[1];
  const float* Wout = (const float*)d_in[2];
  float* outp = (float*)d_out;
  char* ws = (char*)d_ws;
  const size_t MB = 1024 * 1024;
  bf16* xb    = (bf16*)(ws);             // 8 MB [4096][1024]; later reused as attn out
  bf16* wqkvT = (bf16*)(ws + 8 * MB);    // 6 MB [3072][1024]
  bf16* woutT = (bf16*)(ws + 14 * MB);   // 2 MB [1024][1024]
  bf16* qb    = (bf16*)(ws + 16 * MB);   // 8 MB [32][2048][64] (scaled 0.125*log2e)
  bf16* kb    = (bf16*)(ws + 24 * MB);   // 8 MB [32][2048][64]
  bf16* vtb   = (bf16*)(ws + 32 * MB);   // 8 MB [32][64][2048]

  hipLaunchKernelGGL(prep, dim3(6144), dim3(256), 0, stream,
                     x, Wqkv, Wout, xb, wqkvT, woutT);
  hipLaunchKernelGGL(gemm_qkv, dim3(768), dim3(256), 0, stream,
                     xb, wqkvT, qb, kb, vtb);
  hipLaunchKernelGGL(attn, dim3(512), dim3(256), 0, stream,
                     qb, kb, vtb, xb);
  hipLaunchKernelGGL(gemm_out, dim3(512), dim3(256), 0, stream,
                     xb, woutT, outp);
}

// Round 17
// 89.701 us; speedup vs baseline: 1.1505x; 1.1306x over previous
//
#include <hip/hip_runtime.h>
#include <hip/hip_bf16.h>

typedef __bf16 bf16;
typedef bf16 bf16x4 __attribute__((ext_vector_type(4)));
typedef bf16 bf16x8 __attribute__((ext_vector_type(8)));
typedef float f32x4 __attribute__((ext_vector_type(4)));
typedef float f32x16 __attribute__((ext_vector_type(16)));
typedef unsigned int u32x4 __attribute__((ext_vector_type(4)));

#define GLOAD16(g, l) __builtin_amdgcn_global_load_lds( \
    (const __attribute__((address_space(1))) void*)(g),  \
    (__attribute__((address_space(3))) void*)(l), 16, 0, 0)

#define EXP2F(x) __builtin_amdgcn_exp2f(x)
#define MFMA16(a, b, c) __builtin_amdgcn_mfma_f32_16x16x32_bf16(a, b, c, 0, 0, 0)
#define MFMA32(a, b, c) __builtin_amdgcn_mfma_f32_32x32x16_bf16(a, b, c, 0, 0, 0)

// ---------------- prep: cast x + transpose-cast both weights ----------------
__global__ __launch_bounds__(256) void prep(const float* __restrict__ x,
                                            const float* __restrict__ Wqkv,
                                            const float* __restrict__ Wout,
                                            bf16* __restrict__ xb,
                                            bf16* __restrict__ wqkvT,
                                            bf16* __restrict__ woutT) {
  int id = blockIdx.x, tid = threadIdx.x;
  if (id < 2048) {
    int i = id * 256 + tid;
    const float4* p = (const float4*)x + (size_t)i * 2;
    float4 a = p[0], b = p[1];
    bf16x8 o;
    o[0] = (bf16)a.x; o[1] = (bf16)a.y; o[2] = (bf16)a.z; o[3] = (bf16)a.w;
    o[4] = (bf16)b.x; o[5] = (bf16)b.y; o[6] = (bf16)b.z; o[7] = (bf16)b.w;
    ((bf16x8*)xb)[i] = o;
  } else {
    __shared__ float tile[32][33];
    const float* src; bf16* dst; int N, j;
    if (id < 5120) { src = Wqkv; dst = wqkvT; N = 3072; j = id - 2048; }
    else           { src = Wout; dst = woutT; N = 1024; j = id - 5120; }
    int ntile = N / 32;
    int n0 = (j % ntile) * 32, k0 = (j / ntile) * 32;
    int tx = tid & 31, ty = tid >> 5;   // 32 x 8
#pragma unroll
    for (int i = 0; i < 4; i++)
      tile[ty + 8 * i][tx] = src[(size_t)(k0 + ty + 8 * i) * N + n0 + tx];
    __syncthreads();
#pragma unroll
    for (int i = 0; i < 4; i++)
      dst[(size_t)(n0 + ty + 8 * i) * 1024 + k0 + tx] = (bf16)tile[tx][ty + 8 * i];
  }
}

// ---- GEMM mainloop BK=64 (round-6 proven): C[128,128] += A * Bt^T ----
__device__ __forceinline__ void gemm_mainloop64(const bf16* __restrict__ A,
                                                const bf16* __restrict__ Bt,
                                                int K, int m0, int n0,
                                                f32x4 acc[4][4],
                                                bf16* As, bf16* Bs) {
  int tid = threadIdx.x;
  int lane = tid & 63;
  int wave = tid >> 6;
  int wr = wave >> 1, wc = wave & 1;
  int c16 = lane & 15, g = lane >> 4;
  f32x4 z = {0.f, 0.f, 0.f, 0.f};
#pragma unroll
  for (int m = 0; m < 4; m++)
#pragma unroll
    for (int n = 0; n < 4; n++) acc[m][n] = z;
  for (int k0 = 0; k0 < K; k0 += 64) {
#pragma unroll
    for (int i = 0; i < 4; i++) {
      int cc = tid + i * 256;          // 0..1023 chunks of 16B
      int r = cc >> 3, ch = cc & 7;
      int sc = ch ^ (r & 7);
      GLOAD16(A + (size_t)(m0 + r) * K + k0 + sc * 8, As + cc * 8);
    }
#pragma unroll
    for (int i = 0; i < 4; i++) {
      int cc = tid + i * 256;
      int r = cc >> 3, ch = cc & 7;
      int sc = ch ^ (r & 7);
      GLOAD16(Bt + (size_t)(n0 + r) * K + k0 + sc * 8, Bs + cc * 8);
    }
    __syncthreads();
#pragma unroll
    for (int h = 0; h < 2; h++) {
      bf16x8 af[4], bfr[4];
#pragma unroll
      for (int m = 0; m < 4; m++) {
        int ar = wr * 64 + m * 16 + c16;
        af[m] = *(const bf16x8*)((const char*)As + ar * 128 + (((h * 4 + g) ^ (ar & 7)) << 4));
      }
#pragma unroll
      for (int n = 0; n < 4; n++) {
        int br = wc * 64 + n * 16 + c16;
        bfr[n] = *(const bf16x8*)((const char*)Bs + br * 128 + (((h * 4 + g) ^ (br & 7)) << 4));
      }
      __builtin_amdgcn_s_setprio(1);
#pragma unroll
      for (int m = 0; m < 4; m++)
#pragma unroll
        for (int n = 0; n < 4; n++)
          acc[m][n] = MFMA16(af[m], bfr[n], acc[m][n]);
      __builtin_amdgcn_s_setprio(0);
    }
    __syncthreads();
  }
}

// ---- QKV GEMM: x[4096,1024] @ WqkvT[3072,1024]^T -> q,k scaled / vT ----
__global__ __launch_bounds__(256) void gemm_qkv(const bf16* __restrict__ A,
                                                const bf16* __restrict__ Bt,
                                                bf16* __restrict__ q,
                                                bf16* __restrict__ kk,
                                                bf16* __restrict__ vt) {
  __shared__ bf16 As[128 * 64];
  __shared__ bf16 Bs[128 * 64];
  int id = blockIdx.x;
  int xc = id & 7, k = id >> 3;            // k in [0,96)
  int bn = xc * 3 + (k % 3), bm = k / 3;   // bijective: bn [0,24), bm [0,32)
  int m0 = bm * 128, n0 = bn * 128;
  f32x4 acc[4][4];
  gemm_mainloop64(A, Bt, 1024, m0, n0, acc, As, Bs);
  int lane = threadIdx.x & 63;
  int wave = threadIdx.x >> 6;
  int wr = wave >> 1, wc = wave & 1;
  int c16 = lane & 15, g = lane >> 4;
  int which = n0 >> 10;
  const float QSCALE = 0.125f * 1.4426950408889634f;
  if (which == 2) {
#pragma unroll
    for (int m = 0; m < 4; m++)
#pragma unroll
      for (int n = 0; n < 4; n++) {
        int gm0 = m0 + wr * 64 + m * 16 + g * 4;
        int gn = n0 + wc * 64 + n * 16 + c16;
        int rem = gn & 1023, h = rem >> 6, d = rem & 63;
        int b = gm0 >> 11, t0 = gm0 & 2047;
        size_t bh = (size_t)(b * 16 + h);
        bf16x4 pv;
        pv[0] = (bf16)acc[m][n][0]; pv[1] = (bf16)acc[m][n][1];
        pv[2] = (bf16)acc[m][n][2]; pv[3] = (bf16)acc[m][n][3];
        *(bf16x4*)(vt + (bh * 64 + d) * 2048 + t0) = pv;
      }
  } else {
#pragma unroll
    for (int m = 0; m < 4; m++)
#pragma unroll
      for (int n = 0; n < 4; n++)
#pragma unroll
        for (int j = 0; j < 4; j++) {
          int gm = m0 + wr * 64 + m * 16 + g * 4 + j;
          int gn = n0 + wc * 64 + n * 16 + c16;
          int rem = gn & 1023, h = rem >> 6, d = rem & 63;
          int b = gm >> 11, t = gm & 2047;
          float v = acc[m][n][j];
          size_t bh = (size_t)(b * 16 + h);
          if (which == 0) q[(bh * 2048 + t) * 64 + d]  = (bf16)(v * QSCALE);
          else            kk[(bh * 2048 + t) * 64 + d] = (bf16)v;
        }
  }
}

// ---- final GEMM: attn[4096,1024] @ WoutT[1024,1024]^T -> out fp32 ----
// 64x128 tiles, grid 512 = 2 blocks/CU.
__global__ __launch_bounds__(256) void gemm_out(const bf16* __restrict__ A,
                                                const bf16* __restrict__ Bt,
                                                float* __restrict__ C) {
  __shared__ bf16 As[64 * 64];    // 8 KB
  __shared__ bf16 Bs[128 * 64];   // 16 KB
  int tid = threadIdx.x;
  int lane = tid & 63;
  int wave = tid >> 6;
  int wr = wave >> 1, wc = wave & 1;
  int c16 = lane & 15, g = lane >> 4;
  int id = blockIdx.x;
  int bn = id & 7, bm = id >> 3;      // bm 0..63
  int m0 = bm * 64, n0 = bn * 128;
  const int K = 1024;
  f32x4 acc[2][4];
  {
    f32x4 z = {0.f, 0.f, 0.f, 0.f};
#pragma unroll
    for (int m = 0; m < 2; m++)
#pragma unroll
      for (int n = 0; n < 4; n++) acc[m][n] = z;
  }
  for (int k0 = 0; k0 < K; k0 += 64) {
#pragma unroll
    for (int i = 0; i < 2; i++) {   // A tile 64x64 = 512 chunks
      int cc = tid + i * 256;
      int r = cc >> 3, ch = cc & 7;
      int sc = ch ^ (r & 7);
      GLOAD16(A + (size_t)(m0 + r) * K + k0 + sc * 8, As + cc * 8);
    }
#pragma unroll
    for (int i = 0; i < 4; i++) {   // B tile 128x64 = 1024 chunks
      int cc = tid + i * 256;
      int r = cc >> 3, ch = cc & 7;
      int sc = ch ^ (r & 7);
      GLOAD16(Bt + (size_t)(n0 + r) * K + k0 + sc * 8, Bs + cc * 8);
    }
    __syncthreads();
#pragma unroll
    for (int h = 0; h < 2; h++) {
      bf16x8 af[2], bfr[4];
#pragma unroll
      for (int m = 0; m < 2; m++) {
        int ar = wr * 32 + m * 16 + c16;
        af[m] = *(const bf16x8*)((const char*)As + ar * 128 + (((h * 4 + g) ^ (ar & 7)) << 4));
      }
#pragma unroll
      for (int n = 0; n < 4; n++) {
        int br = wc * 64 + n * 16 + c16;
        bfr[n] = *(const bf16x8*)((const char*)Bs + br * 128 + (((h * 4 + g) ^ (br & 7)) << 4));
      }
      __builtin_amdgcn_s_setprio(1);
#pragma unroll
      for (int m = 0; m < 2; m++)
#pragma unroll
        for (int n = 0; n < 4; n++)
          acc[m][n] = MFMA16(af[m], bfr[n], acc[m][n]);
      __builtin_amdgcn_s_setprio(0);
    }
    __syncthreads();
  }
#pragma unroll
  for (int m = 0; m < 2; m++)
#pragma unroll
    for (int n = 0; n < 4; n++)
#pragma unroll
      for (int j = 0; j < 4; j++) {
        int gm = m0 + wr * 32 + m * 16 + g * 4 + j;
        int gn = n0 + wc * 64 + n * 16 + c16;
        C[(size_t)gm * 1024 + gn] = acc[m][n][j];
      }
}

// ---------------- flash attention v14 (parity-split waves, 32x32 MFMA) ----------------
// 512 blocks x 512 thr (8 waves). Wave w = (qw = w&3, par = w>>2): owns q rows
// [q0+32qw, +32) and processes s-tiles of parity par only. Fixed-max softmax
// makes O/l ADDITIVE over disjoint key sets, so the two parity partials are
// summed at the end via LDS (reusing dead K/V space). Doubles waves/SIMD
// (2 -> 4) while keeping v13's 32-row K/V amortization + in-register P.
__global__ __launch_bounds__(512, 4) void attn(const bf16* __restrict__ q,
                                               const bf16* __restrict__ kk,
                                               const bf16* __restrict__ vt,
                                               bf16* __restrict__ out) {
  __shared__ __align__(16) char smem[65536];   // 4x8KB K | 4x8KB V; reused as xch
  bf16* Ks = (bf16*)smem;               // Ks + b*4096
  bf16* Vs = (bf16*)(smem + 32768);     // Vs + b*4096
  int tid = threadIdx.x, lane = tid & 63, w = tid >> 6;
  int qw = w & 3, par = w >> 2;
  int ql = lane & 31, hi = lane >> 5;

  // ---- XCD-aware decode (bijection on 512 blocks) ----
  int id = blockIdx.x;
  int c = id & 7;
  int k = id >> 3;
  int s = k >> 5;
  int j5 = k & 31;
  int bxi = j5 & 15, b2 = j5 >> 4;
  int bx = s ? (15 - bxi) : bxi;       // pairs sum to 15 (load balance)
  int bh = 4 * c + 2 * b2 + s;         // 4 bh per XCD (K/V L2-resident)
  int q0 = bx * 128;

  const bf16* qb = q  + (size_t)bh * 2048 * 64;
  const bf16* kb = kk + (size_t)bh * 2048 * 64;
  const bf16* vb = vt + (size_t)bh * 64 * 2048;
  int nt = 2 * bx + 2;              // even
  int ns = nt >> 1;

  int qlo = q0 + qw * 32;           // wave owns q rows [qlo, qlo+32)
  int qg = qlo + ql;                // this lane's q row

  // ---- Q frags to registers: B-operand, col q=ql, k d = j*16 + hi*8 + e ----
  bf16x8 qf[4];
#pragma unroll
  for (int j = 0; j < 4; j++)
    qf[j] = *(const bf16x8*)(qb + (size_t)qg * 64 + j * 16 + hi * 8);

  // ---- stage K/V tiles 0,1 (512 thr: one 16B chunk per tile each) ----
  {
    int cc = tid;                    // 0..511
    int r = cc >> 3;
    int sw = ((cc & 7) ^ (r & 7)) * 8;
    GLOAD16(kb + (size_t)r * 64 + sw, Ks + cc * 8);
    GLOAD16(vb + (size_t)r * 2048 + sw, Vs + cc * 8);
    GLOAD16(kb + (size_t)(64 + r) * 64 + sw, Ks + 4096 + cc * 8);
    GLOAD16(vb + (size_t)r * 2048 + 64 + sw, Vs + 4096 + cc * 8);
  }
  __syncthreads();

  f32x16 o[2];
#pragma unroll
  for (int i = 0; i < 16; i++) { o[0][i] = 0.f; o[1][i] = 0.f; }
  float lsum = 0.f;

  for (int st = 0; st < ns; ++st) {
    if (st + 1 < ns) {              // prefetch next pair of tiles
      int sn = st * 128 + 128;
      int nb = (2 * st + 2) & 3;    // and nb+1
      int cc = tid;
      int r = cc >> 3;
      int sw = ((cc & 7) ^ (r & 7)) * 8;
      GLOAD16(kb + (size_t)(sn + r) * 64 + sw, Ks + nb * 4096 + cc * 8);
      GLOAD16(vb + (size_t)r * 2048 + sn + sw, Vs + nb * 4096 + cc * 8);
      GLOAD16(kb + (size_t)(sn + 64 + r) * 64 + sw, Ks + (nb + 1) * 4096 + cc * 8);
      GLOAD16(vb + (size_t)r * 2048 + sn + 64 + sw, Vs + (nb + 1) * 4096 + cc * 8);
    }
    int t = 2 * st + par;            // this wave's tile this interval
    int s0 = t * 64;
    if (s0 <= qlo + 31) {            // wave-uniform causal skip
      const char* Kb = (const char*)(Ks + (t & 3) * 4096);
      const char* Vb = (const char*)(Vs + (t & 3) * 4096);
      // ---- QK^T: S[sb] col q=ql, row s = sb*32 + (r&3)+8*(r>>2)+4*hi ----
      f32x16 S[2];
#pragma unroll
      for (int i = 0; i < 16; i++) { S[0][i] = 0.f; S[1][i] = 0.f; }
      __builtin_amdgcn_s_setprio(1);
#pragma unroll
      for (int j = 0; j < 4; j++) {    // k-step over d
        int row0 = ql, row1 = 32 + ql;
        bf16x8 kf0 = *(const bf16x8*)(Kb + row0 * 128 + (((2 * j + hi) ^ (row0 & 7)) << 4));
        bf16x8 kf1 = *(const bf16x8*)(Kb + row1 * 128 + (((2 * j + hi) ^ (row1 & 7)) << 4));
        S[0] = MFMA32(kf0, qf[j], S[0]);
        S[1] = MFMA32(kf1, qf[j], S[1]);
      }
      __builtin_amdgcn_s_setprio(0);
      // ---- causal mask (diag tiles only, wave-uniform test) ----
      if (s0 + 63 > qlo) {
#pragma unroll
        for (int sb = 0; sb < 2; sb++)
#pragma unroll
          for (int r = 0; r < 16; r++) {
            int sg = s0 + sb * 32 + (r & 3) + 8 * (r >> 2) + 4 * hi;
            if (sg > qg) S[sb][r] = -__builtin_inff();
          }
      }
      // ---- fixed-max softmax: P = exp2(S) in place; per-lane l partial ----
#pragma unroll
      for (int sb = 0; sb < 2; sb++)
#pragma unroll
        for (int r = 0; r < 16; r++) {
          float pv2 = EXP2F(S[sb][r]);
          S[sb][r] = pv2;
          lsum += pv2;
        }
      // ---- PV: per k-step j (s 16j..16j+15): build P^T B-frag in regs ----
      __builtin_amdgcn_s_setprio(1);
#pragma unroll
      for (int j = 0; j < 4; j++) {
        int sb = j >> 1, rb = (j & 1) * 8;
        unsigned pa, pb, pc, pd;
        asm("v_cvt_pk_bf16_f32 %0, %1, %2" : "=v"(pa) : "v"(S[sb][rb + 0]), "v"(S[sb][rb + 1]));
        asm("v_cvt_pk_bf16_f32 %0, %1, %2" : "=v"(pb) : "v"(S[sb][rb + 2]), "v"(S[sb][rb + 3]));
        asm("v_cvt_pk_bf16_f32 %0, %1, %2" : "=v"(pc) : "v"(S[sb][rb + 4]), "v"(S[sb][rb + 5]));
        asm("v_cvt_pk_bf16_f32 %0, %1, %2" : "=v"(pd) : "v"(S[sb][rb + 6]), "v"(S[sb][rb + 7]));
        asm("v_permlane32_swap_b32 %0, %1" : "+v"(pa), "+v"(pc));
        asm("v_permlane32_swap_b32 %0, %1" : "+v"(pb), "+v"(pd));
        union { u32x4 u; bf16x8 h; } pu;
        pu.u[0] = pa; pu.u[1] = pb; pu.u[2] = pc; pu.u[3] = pd;
        int row0 = ql, row1 = 32 + ql;
        bf16x8 vf0 = *(const bf16x8*)(Vb + row0 * 128 + (((2 * j + hi) ^ (row0 & 7)) << 4));
        bf16x8 vf1 = *(const bf16x8*)(Vb + row1 * 128 + (((2 * j + hi) ^ (row1 & 7)) << 4));
        o[0] = MFMA32(vf0, pu.h, o[0]);
        o[1] = MFMA32(vf1, pu.h, o[1]);
      }
      __builtin_amdgcn_s_setprio(0);
    }
    if (st + 1 < ns) {
      asm volatile("s_waitcnt vmcnt(0)" ::: "memory");  // next pair staged
      __builtin_amdgcn_s_barrier();
      __builtin_amdgcn_sched_barrier(0);
    }
  }
  // ---- combine parity partials (O/l additive under fixed-max softmax) ----
  lsum += __shfl_xor(lsum, 32);      // merge s-halves within wave
  __syncthreads();                   // all compute done; smem reusable
  float* xch = (float*)smem;         // 4 qw x 64 lanes x 33 floats (stride 33: 2-way free)
  if (par == 1) {
    float* dst = xch + (qw * 64 + lane) * 33;
#pragma unroll
    for (int db = 0; db < 2; db++)
#pragma unroll
      for (int i = 0; i < 16; i++) dst[db * 16 + i] = o[db][i];
    dst[32] = lsum;
  }
  __syncthreads();
  if (par == 0) {
    const float* src = xch + (qw * 64 + lane) * 33;
#pragma unroll
    for (int db = 0; db < 2; db++)
#pragma unroll
      for (int i = 0; i < 16; i++) o[db][i] += src[db * 16 + i];
    lsum += src[32];
    float inv = 1.f / lsum;
    int b = bh >> 4, h = bh & 15;
    size_t rowbase = ((size_t)(b * 2048 + qg)) * 1024 + h * 64;
#pragma unroll
    for (int db = 0; db < 2; db++)
#pragma unroll
      for (int qd = 0; qd < 4; qd++) {
        bf16x4 pv;
#pragma unroll
        for (int i = 0; i < 4; i++) pv[i] = (bf16)(o[db][4 * qd + i] * inv);
        *(bf16x4*)(out + rowbase + db * 32 + 8 * qd + 4 * hi) = pv;
      }
  }
}

extern "C" void kernel_launch(void* const* d_in, const int* in_sizes, int n_in,
                              void* d_out, int out_size, void* d_ws, size_t ws_size,
                              hipStream_t stream) {
  const float* x    = (const float*)d_in[0];
  const float* Wqkv = (const float*)d_in[1];
  const float* Wout = (const float*)d_in[2];
  float* outp = (float*)d_out;
  char* ws = (char*)d_ws;
  const size_t MB = 1024 * 1024;
  bf16* xb    = (bf16*)(ws);             // 8 MB [4096][1024]; later reused as attn out
  bf16* wqkvT = (bf16*)(ws + 8 * MB);    // 6 MB [3072][1024]
  bf16* woutT = (bf16*)(ws + 14 * MB);   // 2 MB [1024][1024]
  bf16* qb    = (bf16*)(ws + 16 * MB);   // 8 MB [32][2048][64] (scaled 0.125*log2e)
  bf16* kb    = (bf16*)(ws + 24 * MB);   // 8 MB [32][2048][64]
  bf16* vtb   = (bf16*)(ws + 32 * MB);   // 8 MB [32][64][2048]

  hipLaunchKernelGGL(prep, dim3(6144), dim3(256), 0, stream,
                     x, Wqkv, Wout, xb, wqkvT, woutT);
  hipLaunchKernelGGL(gemm_qkv, dim3(768), dim3(256), 0, stream,
                     xb, wqkvT, qb, kb, vtb);
  hipLaunchKernelGGL(attn, dim3(512), dim3(512), 0, stream,
                     qb, kb, vtb, xb);
  hipLaunchKernelGGL(gemm_out, dim3(512), dim3(256), 0, stream,
                     xb, woutT, outp);
}